// Round 1
// baseline (434.727 us; speedup 1.0000x reference)
//
#include <hip/hip_runtime.h>
#include <hip/hip_fp16.h>
#include <math.h>

#define NNODES 40000
#define NEDGES 640000
#define NGRAPH 64
#define CAP 96                 // slots per dst bucket (max random-degree ~45)
constexpr float LN_EPS = 1e-5f;

// ================= butterfly wave reduction (all lanes get result) =================
__device__ __forceinline__ float bf_sum(float v) {
    #pragma unroll
    for (int o = 32; o > 0; o >>= 1) v += __shfl_xor(v, o);
    return v;
}

// ================= prep: zero cnt/sums + transpose W1,W2 (one kernel) =================
__global__ void prep(const float* __restrict__ W1, const float* __restrict__ W2,
                     float* __restrict__ Wt1, float* __restrict__ Wt2,
                     int* __restrict__ cnt, float* __restrict__ sums) {
    int t = blockIdx.x * 256 + threadIdx.x;
    if (t < NNODES) cnt[t] = 0;
    if (t < 128 * 128) { int o = t / 128, i = t % 128; Wt1[i * 128 + o] = W1[t]; }
    if (t < 64 * 128)  { int o = t / 128, i = t % 128; Wt2[i * 64 + o] = W2[t]; }
    if (t < NGRAPH * 64) sums[t] = 0.f;
}

// ================= binning (random edges only; self-loops analytic) =================
__global__ void bin_edges(const int* __restrict__ ei, int E,
                          int* __restrict__ cnt, unsigned short* __restrict__ ssrc) {
    int e = blockIdx.x * blockDim.x + threadIdx.x;
    if (e >= E) return;
    int s = ei[e], d = ei[E + e];
    int pos = atomicAdd(cnt + d, 1);
    if (pos < CAP) ssrc[d * CAP + pos] = (unsigned short)s;
}

// ================= GEMM + scores: register-tiled 4ch x NPT nodes per thread =========
template<int DIN, int DOUT, int NPT>
__global__ __launch_bounds__(256) void gemm_scores(
        const float* __restrict__ X, const float* __restrict__ Wt,
        const float* __restrict__ asrc, const float* __restrict__ adst,
        __half* __restrict__ H, float* __restrict__ S, float* __restrict__ Dv) {
    constexpr int CHG = DOUT / 4;        // threads along channel dim
    constexpr int NG  = 256 / CHG;       // node-groups per block
    constexpr int NPB = NG * NPT;        // nodes per block
    static_assert(NPB == 64, "NPB must be 64");
    __shared__ float xs[DIN][NPB];
    __shared__ float ps[NG][NPT][2];
    const int base = blockIdx.x * NPB;
    const int tid = threadIdx.x;
    #pragma unroll
    for (int i4 = tid; i4 < NPB * DIN / 4; i4 += 256) {
        const int nd = i4 % NPB, c4 = i4 / NPB;
        float4 v = *(const float4*)(X + (size_t)(base + nd) * DIN + 4 * c4);
        xs[4 * c4 + 0][nd] = v.x;
        xs[4 * c4 + 1][nd] = v.y;
        xs[4 * c4 + 2][nd] = v.z;
        xs[4 * c4 + 3][nd] = v.w;
    }
    __syncthreads();
    const int cg = tid % CHG, ng = tid / CHG;
    const int c0 = 4 * cg, n0 = ng * NPT;
    float acc[NPT][4];
    #pragma unroll
    for (int n = 0; n < NPT; ++n)
        #pragma unroll
        for (int k = 0; k < 4; ++k) acc[n][k] = 0.f;
    #pragma unroll 2
    for (int i = 0; i < DIN; ++i) {
        const float4 w = *(const float4*)(Wt + i * DOUT + c0);
        #pragma unroll
        for (int n4 = 0; n4 < NPT / 4; ++n4) {
            const float4 xv = *(const float4*)&xs[i][n0 + 4 * n4];
            const float xf[4] = {xv.x, xv.y, xv.z, xv.w};
            #pragma unroll
            for (int j = 0; j < 4; ++j) {
                const int n = 4 * n4 + j;
                acc[n][0] += xf[j] * w.x; acc[n][1] += xf[j] * w.y;
                acc[n][2] += xf[j] * w.z; acc[n][3] += xf[j] * w.w;
            }
        }
    }
    #pragma unroll
    for (int n = 0; n < NPT; ++n) {
        __half2 p01 = __floats2half2_rn(acc[n][0], acc[n][1]);
        __half2 p23 = __floats2half2_rn(acc[n][2], acc[n][3]);
        __half2* hp = (__half2*)(H + (size_t)(base + n0 + n) * DOUT + c0);
        hp[0] = p01; hp[1] = p23;
    }
    const float4 asf = *(const float4*)(asrc + c0);
    const float4 adf = *(const float4*)(adst + c0);
    float sp[NPT], dp[NPT];
    #pragma unroll
    for (int n = 0; n < NPT; ++n) {
        sp[n] = acc[n][0]*asf.x + acc[n][1]*asf.y + acc[n][2]*asf.z + acc[n][3]*asf.w;
        dp[n] = acc[n][0]*adf.x + acc[n][1]*adf.y + acc[n][2]*adf.z + acc[n][3]*adf.w;
    }
    #pragma unroll
    for (int o = CHG / 2; o > 0; o >>= 1) {
        #pragma unroll
        for (int n = 0; n < NPT; ++n) {
            sp[n] += __shfl_xor(sp[n], o);
            dp[n] += __shfl_xor(dp[n], o);
        }
    }
    if (cg == 0) {
        #pragma unroll
        for (int n = 0; n < NPT; ++n) { ps[ng][n][0] = sp[n]; ps[ng][n][1] = dp[n]; }
    }
    __syncthreads();
    if (tid < NPB) {
        S[base + tid]  = ps[tid / NPT][tid % NPT][0];
        Dv[base + tid] = ps[tid / NPT][tid % NPT][1];
    }
}

// ================= fused GAT: 1 node/wave, MULTI-EDGE-PER-LOAD layout ===============
// R(this): D64 and D128 aggr both took 60us despite 2x byte difference -> NOT
// line/byte bound; per-edge fixed cost (1 load instr + 2 readlane + addr VALU per
// edge) is the wall. New layout: EPS_ edges share one wave-wide load (2 for D=128,
// 4 for D=64, 8B/lane), and {src,alpha} broadcast comes from one ds_read_b64 per
// step instead of 2 readlanes per edge. Lines/bytes unchanged by design.
template<int D, int POOL>
__global__ __launch_bounds__(256) void gat_aggr(
        const int* __restrict__ cnt, const unsigned short* __restrict__ ssrc,
        const float* __restrict__ S, const float* __restrict__ Dv,
        const __half* __restrict__ H,
        const float* __restrict__ b, const float* __restrict__ gam,
        const float* __restrict__ bet,
        float* __restrict__ out, const int* __restrict__ batch,
        float* __restrict__ sums) {
    constexpr int EPS_  = (D == 128) ? 2 : 4;     // edges per load instruction
    constexpr int SUBW  = 64 / EPS_;              // lanes per edge slot (32 or 16)
    constexpr int BATCH = (D == 128) ? 8 : 4;     // steps in flight (16 edges/batch)
    __shared__ int2 sa_lds[4][64];                // per-wave {src, alpha} scratch

    const int lane = threadIdx.x & 63;
    const int wv   = threadIdx.x >> 6;
    const int node = blockIdx.x * 4 + wv;         // 1 node per wave
    const int deg = min(__builtin_amdgcn_readfirstlane(cnt[node]), CAP);
    const float dsc = Dv[node];
    float ts = S[node] + dsc;
    ts = ts > 0.f ? ts : 0.2f * ts;
    const float aself = __expf(ts);               // analytic self-loop term

    const int sub = lane % SUBW;                  // channel-group within edge slot
    const int eh  = lane / SUBW;                  // which edge of the group

    float acc[4] = {0.f, 0.f, 0.f, 0.f};          // 4 channels/lane: 4*sub..4*sub+3
    float z;

    if (deg <= 64) {
        // ---- phase 1: gather scores; write padded {src, alpha} pairs to LDS ----
        int s = node; float a = 0.f;              // pad: self row, zero weight
        if (lane < deg) {
            s = ssrc[node * CAP + lane];
            float t = S[s] + dsc;
            t = t > 0.f ? t : 0.2f * t;
            a = __expf(t);
        }
        z = bf_sum(a);
        sa_lds[wv][lane] = make_int2(s, __float_as_int(a));
        // same-wave LDS producer/consumer: lgkmcnt ordering, no barrier needed

        // ---- phase 2: EPS_ edges per load, BATCH steps in flight ----
        const int steps = (deg + EPS_ - 1) / EPS_;
        const int nb = (steps + BATCH - 1) & ~(BATCH - 1);   // idx max 63 (padded)
        for (int j = 0; j < nb; j += BATCH) {
            int2 sa[BATCH]; float2 hv[BATCH];
            #pragma unroll
            for (int u = 0; u < BATCH; ++u)
                sa[u] = sa_lds[wv][(j + u) * EPS_ + eh];
            #pragma unroll
            for (int u = 0; u < BATCH; ++u) {
                const __half* hp = H + (size_t)sa[u].x * D;
                hv[u] = *(const float2*)(hp + 4 * sub);      // 4 halfs = 4 channels
            }
            #pragma unroll
            for (int u = 0; u < BATCH; ++u) {
                const float av = __int_as_float(sa[u].y);
                const __half2* h2p = (const __half2*)&hv[u];
                const float2 f0 = __half22float2(h2p[0]);
                const float2 f1 = __half22float2(h2p[1]);
                acc[0] += av * f0.x; acc[1] += av * f0.y;
                acc[2] += av * f1.x; acc[3] += av * f1.y;
            }
        }
    } else {
        // ---- rare fallback: chunks of 64 edges, same layout, no deep pipeline ----
        float zz = 0.f;
        for (int b0 = 0; b0 < deg; b0 += 64) {
            const int n = min(64, deg - b0);
            int s = node; float a = 0.f;
            if (lane < n) {
                s = ssrc[node * CAP + b0 + lane];
                float t = S[s] + dsc;
                t = t > 0.f ? t : 0.2f * t;
                a = __expf(t);
            }
            zz += bf_sum(a);
            sa_lds[wv][lane] = make_int2(s, __float_as_int(a));
            const int steps = (n + EPS_ - 1) / EPS_;
            for (int j = 0; j < steps; ++j) {
                const int2 sa = sa_lds[wv][j * EPS_ + eh];
                const __half* hp = H + (size_t)sa.x * D;
                const float2 hvv = *(const float2*)(hp + 4 * sub);
                const float av = __int_as_float(sa.y);
                const __half2* h2p = (const __half2*)&hvv;
                const float2 f0 = __half22float2(h2p[0]);
                const float2 f1 = __half22float2(h2p[1]);
                acc[0] += av * f0.x; acc[1] += av * f0.y;
                acc[2] += av * f1.x; acc[3] += av * f1.y;
            }
        }
        z = zz;
    }

    // ---- combine partial sums across edge slots (mirrors acc across groups) ----
    #pragma unroll
    for (int o = SUBW; o < 64; o <<= 1) {
        #pragma unroll
        for (int k = 0; k < 4; ++k) acc[k] += __shfl_xor(acc[k], o);
    }

    // ---- self-loop contribution (coalesced, identical in all slots) ----
    {
        const __half* hp = H + (size_t)node * D;
        const float2 hvv = *(const float2*)(hp + 4 * sub);
        const __half2* h2p = (const __half2*)&hvv;
        const float2 f0 = __half22float2(h2p[0]);
        const float2 f1 = __half22float2(h2p[1]);
        acc[0] += aself * f0.x; acc[1] += aself * f0.y;
        acc[2] += aself * f1.x; acc[3] += aself * f1.y;
    }
    z += aself;

    // ---- normalize + bias + ReLU + LayerNorm (channels duplicated EPS_ times) ----
    const float zinv = 1.0f / z;
    const float4 bv = *(const float4*)(b + 4 * sub);
    const float bf[4] = {bv.x, bv.y, bv.z, bv.w};
    float vv[4], lsum = 0.f;
    #pragma unroll
    for (int k = 0; k < 4; ++k) {
        vv[k] = fmaxf(acc[k] * zinv + bf[k], 0.f);
        lsum += vv[k];
    }
    const float mu = bf_sum(lsum) / (float)(EPS_ * D);
    float q = 0.f;
    #pragma unroll
    for (int k = 0; k < 4; ++k) { vv[k] -= mu; q += vv[k] * vv[k]; }
    const float rstd = rsqrtf(bf_sum(q) / (float)(EPS_ * D) + LN_EPS);
    const float4 gv = *(const float4*)(gam + 4 * sub);
    const float4 ev = *(const float4*)(bet + 4 * sub);
    const float gf[4] = {gv.x, gv.y, gv.z, gv.w};
    const float ef[4] = {ev.x, ev.y, ev.z, ev.w};
    #pragma unroll
    for (int k = 0; k < 4; ++k) vv[k] = gf[k] * vv[k] * rstd + ef[k];

    if (POOL) {
        const int bg = batch[node];               // uniform per wave
        if (eh == 0) {
            #pragma unroll
            for (int k = 0; k < 4; ++k)
                atomicAdd(&sums[bg * D + 4 * sub + k], vv[k]);
        }
    } else {
        if (eh == 0)
            *(float4*)(out + (size_t)node * D + 4 * sub) =
                make_float4(vv[0], vv[1], vv[2], vv[3]);
    }
}

// ================= head: mean (cnt via binary search on sorted batch) + 2 linears ====
__global__ void final_head(const float* __restrict__ sums, const int* __restrict__ batch,
                           const float* __restrict__ Wl, const float* __restrict__ bl,
                           const float* __restrict__ Wc, const float* __restrict__ bc,
                           float* __restrict__ out) {
    __shared__ float p[64];
    __shared__ float red[64];
    const int g = blockIdx.x, tid = threadIdx.x;
    int lo = 0, hi = NNODES;
    while (lo < hi) { int mid = (lo + hi) >> 1; if (batch[mid] < g) lo = mid + 1; else hi = mid; }
    int lo2 = lo, hi2 = NNODES;
    while (lo2 < hi2) { int mid = (lo2 + hi2) >> 1; if (batch[mid] < g + 1) lo2 = mid + 1; else hi2 = mid; }
    const float cnt = (float)(lo2 - lo);
    p[tid] = sums[g * 64 + tid] / fmaxf(cnt, 1.0f);
    __syncthreads();
    float t = bl[tid];
    #pragma unroll 8
    for (int k = 0; k < 64; ++k) t += Wl[tid * 64 + k] * p[k];
    red[tid] = Wc[tid] * t;
    __syncthreads();
    for (int s = 32; s > 0; s >>= 1) {
        if (tid < s) red[tid] += red[tid + s];
        __syncthreads();
    }
    if (tid == 0) out[g] = red[0] + bc[0];
}

extern "C" void kernel_launch(void* const* d_in, const int* in_sizes, int n_in,
                              void* d_out, int out_size, void* d_ws, size_t ws_size,
                              hipStream_t stream) {
    const int N = NNODES, E = NEDGES, G = NGRAPH;

    const float* x      = (const float*)d_in[0];
    const int*   ei     = (const int*)d_in[1];
    const int*   batch  = (const int*)d_in[2];
    const float* W1     = (const float*)d_in[3];
    const float* a1s    = (const float*)d_in[4];
    const float* a1d    = (const float*)d_in[5];
    const float* b1     = (const float*)d_in[6];
    const float* g1     = (const float*)d_in[7];
    const float* be1    = (const float*)d_in[8];
    const float* W2     = (const float*)d_in[9];
    const float* a2s    = (const float*)d_in[10];
    const float* a2d    = (const float*)d_in[11];
    const float* b2     = (const float*)d_in[12];
    const float* g2     = (const float*)d_in[13];
    const float* be2    = (const float*)d_in[14];
    const float* Wl     = (const float*)d_in[15];
    const float* bl     = (const float*)d_in[16];
    const float* Wc     = (const float*)d_in[17];
    const float* bc     = (const float*)d_in[18];

    // ---- workspace carve-up ----
    char* w = (char*)d_ws;
    __half* h1  = (__half*)w; w += (size_t)N * 128 * 2;   // fp16 H
    float* acc1 = (float*)w; w += (size_t)N * 128 * 4;
    float* S    = (float*)w; w += (size_t)N * 4;
    float* Dv   = (float*)w; w += (size_t)N * 4;
    int* cnt    = (int*)w;   w += (size_t)N * 4;
    unsigned short* ssrc = (unsigned short*)w; w += (size_t)N * CAP * 2;
    float* Wt1  = (float*)w; w += (size_t)128 * 128 * 4;
    float* Wt2  = (float*)w; w += (size_t)128 * 64 * 4;
    float* sums = (float*)w; w += (size_t)G * 64 * 4;
    __half* h2 = h1;

    const int TB = 256;
    const int gridN = (N + 255) / 256;

    // ---- prep (zero cnt/sums + W transposes) ----
    prep<<<gridN, 256, 0, stream>>>(W1, W2, Wt1, Wt2, cnt, sums);

    // ---- edge binning (random edges only; self-loops analytic) ----
    bin_edges<<<(E + TB - 1) / TB, TB, 0, stream>>>(ei, E, cnt, ssrc);

    // ---- layer 1 (128 -> 128) ----
    gemm_scores<128, 128, 8><<<N / 64, 256, 0, stream>>>(x, Wt1, a1s, a1d, h1, S, Dv);
    gat_aggr<128, 0><<<N / 4, 256, 0, stream>>>(cnt, ssrc, S, Dv, h1, b1, g1, be1,
                                                acc1, nullptr, nullptr);

    // ---- layer 2 (128 -> 64), pool fused ----
    gemm_scores<128, 64, 4><<<N / 64, 256, 0, stream>>>(acc1, Wt2, a2s, a2d, h2, S, Dv);
    gat_aggr<64, 1><<<N / 4, 256, 0, stream>>>(cnt, ssrc, S, Dv, h2, b2, g2, be2,
                                               nullptr, batch, sums);

    // ---- head ----
    final_head<<<G, 64, 0, stream>>>(sums, batch, Wl, bl, Wc, bc, (float*)d_out);
}

// Round 2
// 270.610 us; speedup vs baseline: 1.6065x; 1.6065x over previous
//
#include <hip/hip_runtime.h>
#include <hip/hip_fp16.h>
#include <math.h>

#define NNODES 40000
#define NEDGES 640000
#define NGRAPH 64
#define CAP 96                 // slots per dst bucket (max random-degree ~45)
constexpr float LN_EPS = 1e-5f;

// R1 LESSON (measured): packing multiple edges into one wave load (per-lane
// divergent 64-bit addresses) collapsed request throughput: 60us -> 235us,
// HBM 600 -> 280 GB/s at identical FETCH_SIZE. The SGPR-base (readlane) +
// contiguous-lane-offset load, ONE edge per VMEM instruction, is the fast
// path and is kept everywhere below.

// ================= butterfly wave reduction (all lanes get result) =================
__device__ __forceinline__ float bf_sum(float v) {
    #pragma unroll
    for (int o = 32; o > 0; o >>= 1) v += __shfl_xor(v, o);
    return v;
}

// ================= prep: zero cnt/sums + transpose W1,W2 (one kernel) =================
__global__ void prep(const float* __restrict__ W1, const float* __restrict__ W2,
                     float* __restrict__ Wt1, float* __restrict__ Wt2,
                     int* __restrict__ cnt, float* __restrict__ sums) {
    int t = blockIdx.x * 256 + threadIdx.x;
    if (t < NNODES) cnt[t] = 0;
    if (t < 128 * 128) { int o = t / 128, i = t % 128; Wt1[i * 128 + o] = W1[t]; }
    if (t < 64 * 128)  { int o = t / 128, i = t % 128; Wt2[i * 64 + o] = W2[t]; }
    if (t < NGRAPH * 64) sums[t] = 0.f;
}

// ================= binning (random edges only; self-loops analytic) =================
__global__ void bin_edges(const int* __restrict__ ei, int E,
                          int* __restrict__ cnt, unsigned short* __restrict__ ssrc) {
    int e = blockIdx.x * blockDim.x + threadIdx.x;
    if (e >= E) return;
    int s = ei[e], d = ei[E + e];
    int pos = atomicAdd(cnt + d, 1);
    if (pos < CAP) ssrc[d * CAP + pos] = (unsigned short)s;
}

// ================= GEMM + scores: register-tiled 4ch x NPT nodes per thread =========
template<int DIN, int DOUT, int NPT>
__global__ __launch_bounds__(256) void gemm_scores(
        const float* __restrict__ X, const float* __restrict__ Wt,
        const float* __restrict__ asrc, const float* __restrict__ adst,
        __half* __restrict__ H, float* __restrict__ S, float* __restrict__ Dv) {
    constexpr int CHG = DOUT / 4;        // threads along channel dim
    constexpr int NG  = 256 / CHG;       // node-groups per block
    constexpr int NPB = NG * NPT;        // nodes per block
    static_assert(NPB == 64, "NPB must be 64");
    __shared__ float xs[DIN][NPB];
    __shared__ float ps[NG][NPT][2];
    const int base = blockIdx.x * NPB;
    const int tid = threadIdx.x;
    #pragma unroll
    for (int i4 = tid; i4 < NPB * DIN / 4; i4 += 256) {
        const int nd = i4 % NPB, c4 = i4 / NPB;
        float4 v = *(const float4*)(X + (size_t)(base + nd) * DIN + 4 * c4);
        xs[4 * c4 + 0][nd] = v.x;
        xs[4 * c4 + 1][nd] = v.y;
        xs[4 * c4 + 2][nd] = v.z;
        xs[4 * c4 + 3][nd] = v.w;
    }
    __syncthreads();
    const int cg = tid % CHG, ng = tid / CHG;
    const int c0 = 4 * cg, n0 = ng * NPT;
    float acc[NPT][4];
    #pragma unroll
    for (int n = 0; n < NPT; ++n)
        #pragma unroll
        for (int k = 0; k < 4; ++k) acc[n][k] = 0.f;
    #pragma unroll 2
    for (int i = 0; i < DIN; ++i) {
        const float4 w = *(const float4*)(Wt + i * DOUT + c0);
        #pragma unroll
        for (int n4 = 0; n4 < NPT / 4; ++n4) {
            const float4 xv = *(const float4*)&xs[i][n0 + 4 * n4];
            const float xf[4] = {xv.x, xv.y, xv.z, xv.w};
            #pragma unroll
            for (int j = 0; j < 4; ++j) {
                const int n = 4 * n4 + j;
                acc[n][0] += xf[j] * w.x; acc[n][1] += xf[j] * w.y;
                acc[n][2] += xf[j] * w.z; acc[n][3] += xf[j] * w.w;
            }
        }
    }
    #pragma unroll
    for (int n = 0; n < NPT; ++n) {
        __half2 p01 = __floats2half2_rn(acc[n][0], acc[n][1]);
        __half2 p23 = __floats2half2_rn(acc[n][2], acc[n][3]);
        __half2* hp = (__half2*)(H + (size_t)(base + n0 + n) * DOUT + c0);
        hp[0] = p01; hp[1] = p23;
    }
    const float4 asf = *(const float4*)(asrc + c0);
    const float4 adf = *(const float4*)(adst + c0);
    float sp[NPT], dp[NPT];
    #pragma unroll
    for (int n = 0; n < NPT; ++n) {
        sp[n] = acc[n][0]*asf.x + acc[n][1]*asf.y + acc[n][2]*asf.z + acc[n][3]*asf.w;
        dp[n] = acc[n][0]*adf.x + acc[n][1]*adf.y + acc[n][2]*adf.z + acc[n][3]*adf.w;
    }
    #pragma unroll
    for (int o = CHG / 2; o > 0; o >>= 1) {
        #pragma unroll
        for (int n = 0; n < NPT; ++n) {
            sp[n] += __shfl_xor(sp[n], o);
            dp[n] += __shfl_xor(dp[n], o);
        }
    }
    if (cg == 0) {
        #pragma unroll
        for (int n = 0; n < NPT; ++n) { ps[ng][n][0] = sp[n]; ps[ng][n][1] = dp[n]; }
    }
    __syncthreads();
    if (tid < NPB) {
        S[base + tid]  = ps[tid / NPT][tid % NPT][0];
        Dv[base + tid] = ps[tid / NPT][tid % NPT][1];
    }
}

// ================= generic single-node aggregation (any deg; rare big-deg path) =====
template<int D>
__device__ __forceinline__ void aggr_one_generic(
        const int node, const int deg, const int lane,
        const unsigned short* __restrict__ ssrc, const float* __restrict__ S,
        const float dsc, const __half* __restrict__ H,
        float& acc0, float& acc1, float& z) {
    constexpr int VPL = D / 64;
    float zz = 0.f;
    const int r0 = node * CAP;
    for (int bse = 0; bse < deg; bse += 64) {
        const int n = min(64, deg - bse);
        int s = 0; float a = 0.f;
        if (lane < n) {
            s = ssrc[r0 + bse + lane];
            float t = S[s] + dsc;
            t = t > 0.f ? t : 0.2f * t;
            a = __expf(t);
        }
        zz += bf_sum(a);
        const int abits = __float_as_int(a);
        for (int j = 0; j < n; ++j) {
            const int sj = __builtin_amdgcn_readlane(s, j);
            const float aj = __int_as_float(__builtin_amdgcn_readlane(abits, j));
            const __half* hp = H + (size_t)sj * D;
            if (VPL == 1) {
                acc0 += aj * __half2float(hp[lane]);
            } else {
                const float2 f = __half22float2(*(const __half2*)(hp + 2 * lane));
                acc0 += aj * f.x; acc1 += aj * f.y;
            }
        }
    }
    z = zz;
}

// ================= epilogue: self-loop + normalize + bias + ReLU + LN + store =======
template<int D, int POOL>
__device__ __forceinline__ void finish_node(
        const int node, const int lane,
        float acc0, float acc1, float z, const float aself, const float2 selfF,
        const float* __restrict__ b, const float* __restrict__ gam,
        const float* __restrict__ bet,
        float* __restrict__ out, const int* __restrict__ batch,
        float* __restrict__ sums) {
    constexpr int VPL = D / 64;
    acc0 += aself * selfF.x;
    if (VPL == 2) acc1 += aself * selfF.y;
    z += aself;
    const float zinv = 1.0f / z;
    float vv[VPL], lsum = 0.f;
    vv[0] = acc0;
    if (VPL == 2) vv[1] = acc1;
    #pragma unroll
    for (int k = 0; k < VPL; ++k) {
        const int ch = VPL * lane + k;
        vv[k] = fmaxf(vv[k] * zinv + b[ch], 0.f);
        lsum += vv[k];
    }
    const float mu = bf_sum(lsum) / D;
    float q = 0.f;
    #pragma unroll
    for (int k = 0; k < VPL; ++k) { vv[k] -= mu; q += vv[k] * vv[k]; }
    const float rstd = rsqrtf(bf_sum(q) / D + LN_EPS);
    #pragma unroll
    for (int k = 0; k < VPL; ++k) {
        const int ch = VPL * lane + k;
        vv[k] = gam[ch] * vv[k] * rstd + bet[ch];
    }
    if (POOL) {
        const int bg = batch[node];                 // uniform per wave
        atomicAdd(&sums[bg * D + lane], vv[0]);     // POOL only used with D=64
    } else {
        if (VPL == 1) out[(size_t)node * D + lane] = vv[0];
        else *(float2*)(out + (size_t)node * D + 2 * lane) = make_float2(vv[0], vv[1]);
    }
}

// ================= fused GAT: TWO nodes per wave, interleaved chains ================
// R0 counters: VALUBusy 26%, HBM 7.5%, Occ 58% -> latency-bound on the per-node
// serial chain (ssrc row -> S gather -> H batch -> H batch). This version runs two
// independent node chains per wave (A,B), interleaving their loads: 2x round-trips
// in flight at the SAME per-edge SGPR-base addressing (see R1 lesson above).
template<int D, int POOL>
__global__ __launch_bounds__(256) void gat_aggr(
        const int* __restrict__ cnt, const unsigned short* __restrict__ ssrc,
        const float* __restrict__ S, const float* __restrict__ Dv,
        const __half* __restrict__ H,
        const float* __restrict__ b, const float* __restrict__ gam,
        const float* __restrict__ bet,
        float* __restrict__ out, const int* __restrict__ batch,
        float* __restrict__ sums) {
    constexpr int VPL = D / 64;
    const int lane = threadIdx.x & 63;
    const int wv   = threadIdx.x >> 6;
    const int nodeA = blockIdx.x * 8 + wv * 2;      // 2 nodes per wave
    const int nodeB = nodeA + 1;

    const int degA = min(__builtin_amdgcn_readfirstlane(cnt[nodeA]), CAP);
    const int degB = min(__builtin_amdgcn_readfirstlane(cnt[nodeB]), CAP);
    const float dscA = Dv[nodeA], dscB = Dv[nodeB];

    // self-loop score terms
    float tsA = S[nodeA] + dscA; tsA = tsA > 0.f ? tsA : 0.2f * tsA;
    float tsB = S[nodeB] + dscB; tsB = tsB > 0.f ? tsB : 0.2f * tsB;
    const float aselfA = __expf(tsA);
    const float aselfB = __expf(tsB);

    // self H rows (coalesced, issued early so they're resident by the epilogue)
    float2 selfFA, selfFB;
    if (VPL == 1) {
        selfFA = make_float2(__half2float(H[(size_t)nodeA * D + lane]), 0.f);
        selfFB = make_float2(__half2float(H[(size_t)nodeB * D + lane]), 0.f);
    } else {
        selfFA = __half22float2(*(const __half2*)(H + (size_t)nodeA * D + 2 * lane));
        selfFB = __half22float2(*(const __half2*)(H + (size_t)nodeB * D + 2 * lane));
    }

    float accA0 = 0.f, accA1 = 0.f, accB0 = 0.f, accB1 = 0.f;
    float zA, zB;

    if (degA <= 64 && degB <= 64) {
        // ---- phase 1: both ssrc rows, then both S gathers (4 loads overlapped) ----
        int sA = 0, sB = 0;
        if (lane < degA) sA = ssrc[nodeA * CAP + lane];
        if (lane < degB) sB = ssrc[nodeB * CAP + lane];
        float tA = S[sA] + dscA;                    // idle lanes read S[0]: harmless
        float tB = S[sB] + dscB;
        tA = tA > 0.f ? tA : 0.2f * tA;
        tB = tB > 0.f ? tB : 0.2f * tB;
        const float aA = (lane < degA) ? __expf(tA) : 0.f;
        const float aB = (lane < degB) ? __expf(tB) : 0.f;
        zA = bf_sum(aA);
        zB = bf_sum(aB);
        const int abA = __float_as_int(aA), abB = __float_as_int(aB);

        // ---- phase 2: alternate 8-load batches of A and B (16 loads in flight) ----
        const int nmA = (degA + 7) & ~7;
        const int nmB = (degB + 7) & ~7;
        const int nmax = max(nmA, nmB);
        for (int j = 0; j < nmax; j += 8) {
            const bool doA = j < nmA, doB = j < nmB;   // wave-uniform
            float afA[8], afB[8];
            __half2 hvA[8], hvB[8];
            __half hsA[8], hsB[8];
            if (doA) {
                #pragma unroll
                for (int u = 0; u < 8; ++u) {
                    const int sj = __builtin_amdgcn_readlane(sA, j + u);
                    afA[u] = __int_as_float(__builtin_amdgcn_readlane(abA, j + u));
                    const __half* hp = H + (size_t)sj * D;
                    if (VPL == 1) hsA[u] = hp[lane];
                    else          hvA[u] = *(const __half2*)(hp + 2 * lane);
                }
            }
            if (doB) {
                #pragma unroll
                for (int u = 0; u < 8; ++u) {
                    const int sj = __builtin_amdgcn_readlane(sB, j + u);
                    afB[u] = __int_as_float(__builtin_amdgcn_readlane(abB, j + u));
                    const __half* hp = H + (size_t)sj * D;
                    if (VPL == 1) hsB[u] = hp[lane];
                    else          hvB[u] = *(const __half2*)(hp + 2 * lane);
                }
            }
            if (doA) {
                #pragma unroll
                for (int u = 0; u < 8; ++u) {
                    if (VPL == 1) {
                        accA0 += afA[u] * __half2float(hsA[u]);
                    } else {
                        accA0 += afA[u] * __half2float(__low2half(hvA[u]));
                        accA1 += afA[u] * __half2float(__high2half(hvA[u]));
                    }
                }
            }
            if (doB) {
                #pragma unroll
                for (int u = 0; u < 8; ++u) {
                    if (VPL == 1) {
                        accB0 += afB[u] * __half2float(hsB[u]);
                    } else {
                        accB0 += afB[u] * __half2float(__low2half(hvB[u]));
                        accB1 += afB[u] * __half2float(__high2half(hvB[u]));
                    }
                }
            }
        }
    } else {
        // ---- rare: at least one big bucket -> generic chunked path, sequential ----
        aggr_one_generic<D>(nodeA, degA, lane, ssrc, S, dscA, H, accA0, accA1, zA);
        aggr_one_generic<D>(nodeB, degB, lane, ssrc, S, dscB, H, accB0, accB1, zB);
    }

    finish_node<D, POOL>(nodeA, lane, accA0, accA1, zA, aselfA, selfFA,
                         b, gam, bet, out, batch, sums);
    finish_node<D, POOL>(nodeB, lane, accB0, accB1, zB, aselfB, selfFB,
                         b, gam, bet, out, batch, sums);
}

// ================= head: mean (cnt via binary search on sorted batch) + 2 linears ====
__global__ void final_head(const float* __restrict__ sums, const int* __restrict__ batch,
                           const float* __restrict__ Wl, const float* __restrict__ bl,
                           const float* __restrict__ Wc, const float* __restrict__ bc,
                           float* __restrict__ out) {
    __shared__ float p[64];
    __shared__ float red[64];
    const int g = blockIdx.x, tid = threadIdx.x;
    int lo = 0, hi = NNODES;
    while (lo < hi) { int mid = (lo + hi) >> 1; if (batch[mid] < g) lo = mid + 1; else hi = mid; }
    int lo2 = lo, hi2 = NNODES;
    while (lo2 < hi2) { int mid = (lo2 + hi2) >> 1; if (batch[mid] < g + 1) lo2 = mid + 1; else hi2 = mid; }
    const float cnt = (float)(lo2 - lo);
    p[tid] = sums[g * 64 + tid] / fmaxf(cnt, 1.0f);
    __syncthreads();
    float t = bl[tid];
    #pragma unroll 8
    for (int k = 0; k < 64; ++k) t += Wl[tid * 64 + k] * p[k];
    red[tid] = Wc[tid] * t;
    __syncthreads();
    for (int s = 32; s > 0; s >>= 1) {
        if (tid < s) red[tid] += red[tid + s];
        __syncthreads();
    }
    if (tid == 0) out[g] = red[0] + bc[0];
}

extern "C" void kernel_launch(void* const* d_in, const int* in_sizes, int n_in,
                              void* d_out, int out_size, void* d_ws, size_t ws_size,
                              hipStream_t stream) {
    const int N = NNODES, E = NEDGES, G = NGRAPH;

    const float* x      = (const float*)d_in[0];
    const int*   ei     = (const int*)d_in[1];
    const int*   batch  = (const int*)d_in[2];
    const float* W1     = (const float*)d_in[3];
    const float* a1s    = (const float*)d_in[4];
    const float* a1d    = (const float*)d_in[5];
    const float* b1     = (const float*)d_in[6];
    const float* g1     = (const float*)d_in[7];
    const float* be1    = (const float*)d_in[8];
    const float* W2     = (const float*)d_in[9];
    const float* a2s    = (const float*)d_in[10];
    const float* a2d    = (const float*)d_in[11];
    const float* b2     = (const float*)d_in[12];
    const float* g2     = (const float*)d_in[13];
    const float* be2    = (const float*)d_in[14];
    const float* Wl     = (const float*)d_in[15];
    const float* bl     = (const float*)d_in[16];
    const float* Wc     = (const float*)d_in[17];
    const float* bc     = (const float*)d_in[18];

    // ---- workspace carve-up ----
    char* w = (char*)d_ws;
    __half* h1  = (__half*)w; w += (size_t)N * 128 * 2;   // fp16 H
    float* acc1 = (float*)w; w += (size_t)N * 128 * 4;
    float* S    = (float*)w; w += (size_t)N * 4;
    float* Dv   = (float*)w; w += (size_t)N * 4;
    int* cnt    = (int*)w;   w += (size_t)N * 4;
    unsigned short* ssrc = (unsigned short*)w; w += (size_t)N * CAP * 2;
    float* Wt1  = (float*)w; w += (size_t)128 * 128 * 4;
    float* Wt2  = (float*)w; w += (size_t)128 * 64 * 4;
    float* sums = (float*)w; w += (size_t)G * 64 * 4;
    __half* h2 = h1;

    const int TB = 256;
    const int gridN = (N + 255) / 256;

    // ---- prep (zero cnt/sums + W transposes) ----
    prep<<<gridN, 256, 0, stream>>>(W1, W2, Wt1, Wt2, cnt, sums);

    // ---- edge binning (random edges only; self-loops analytic) ----
    bin_edges<<<(E + TB - 1) / TB, TB, 0, stream>>>(ei, E, cnt, ssrc);

    // ---- layer 1 (128 -> 128) ----
    gemm_scores<128, 128, 8><<<N / 64, 256, 0, stream>>>(x, Wt1, a1s, a1d, h1, S, Dv);
    gat_aggr<128, 0><<<N / 8, 256, 0, stream>>>(cnt, ssrc, S, Dv, h1, b1, g1, be1,
                                                acc1, nullptr, nullptr);

    // ---- layer 2 (128 -> 64), pool fused ----
    gemm_scores<128, 64, 4><<<N / 64, 256, 0, stream>>>(acc1, Wt2, a2s, a2d, h2, S, Dv);
    gat_aggr<64, 1><<<N / 8, 256, 0, stream>>>(cnt, ssrc, S, Dv, h2, b2, g2, be2,
                                               nullptr, batch, sums);

    // ---- head ----
    final_head<<<G, 64, 0, stream>>>(sums, batch, Wl, bl, Wc, bc, (float*)d_out);
}